// Round 8
// baseline (45.614 us; speedup 1.0000x reference)
//
#include <hip/hip_runtime.h>

#define BATCH 4096
#define IN_DIM 512
#define OUT_DIM 512
#define NK 4
#define SX (IN_DIM + NK)   // 516 floats per x row
#define BM 64
#define BN 64
#define BK 64
#define KT (IN_DIM / BK)   // 8 K-tiles

typedef short bf16x8 __attribute__((ext_vector_type(8)));
typedef float f32x4 __attribute__((ext_vector_type(4)));

__device__ __forceinline__ unsigned short f2bf(float f) {
    unsigned int u = __float_as_uint(f);
    u = u + 0x7FFFu + ((u >> 16) & 1u);   // round-to-nearest-even
    return (unsigned short)(u >> 16);
}

__device__ __forceinline__ void gload_lds16(const void* g, void* l) {
    __builtin_amdgcn_global_load_lds(
        (const __attribute__((address_space(1))) void*)g,
        (__attribute__((address_space(3))) void*)l, 16, 0, 0);
}

// ---------------- kernel 1: fp32 -> bf16 pre-pass, XCD-homed W ----------------
// W blocks [0,1024): remapped so the block converting columns o of W runs on
// XCD (o/64) == the XCD that mpl_gemm (C0 = (bid&7)*64) reads those columns
// from -> B-tile lines are dirty-resident in the CONSUMER's L2.
// fb blocks [1024,3072): feat fp32->bf16, unmodified mapping.
__global__ __launch_bounds__(256) void convert_kernel(
    const float* __restrict__ x, const float* __restrict__ w,
    unsigned short* __restrict__ wb, unsigned short* __restrict__ fb)
{
    const int bid = blockIdx.x;
    if (bid < 1024) {
        // W path: each block converts 256 float4 = 1024 elems = 2 rows of W[kn][o][:]
        int t = bid & 7;                  // target o-tile (o/64) == XCD
        int j = bid >> 3;                 // 128 blocks per tile: 4 kn x 32
        int b = (j >> 5) * 256 + t * 32 + (j & 31);   // original block index
        int g = b * 256 + threadIdx.x;    // float4 chunk of W
        const float4 v = reinterpret_cast<const float4*>(w)[g];
        unsigned short h[4] = {f2bf(v.x), f2bf(v.y), f2bf(v.z), f2bf(v.w)};
        *reinterpret_cast<uint2*>(&wb[g * 4]) = *reinterpret_cast<const uint2*>(h);
    } else {
        int idx = (bid - 1024) * 256 + threadIdx.x;   // feat chunks: 4096*128
        int row = idx >> 7;
        int c   = (idx & 127) * 4;
        const float4 v = *reinterpret_cast<const float4*>(&x[(size_t)row * SX + c]);
        unsigned short h[4] = {f2bf(v.x), f2bf(v.y), f2bf(v.z), f2bf(v.w)};
        *reinterpret_cast<uint2*>(&fb[row * IN_DIM + c]) = *reinterpret_cast<const uint2*>(h);
    }
}

// ------- kernel 2: counted-vmcnt pipelined GEMM + XCD-column affinity -------
// (byte-identical compute structure to round 7)
__global__ __launch_bounds__(256) void mpl_gemm(
    const unsigned short* __restrict__ fb,   // (4096,512) bf16
    const unsigned short* __restrict__ wb,   // (4,512,512) bf16
    const float* __restrict__ x,             // (4096,516) fp32 (for p)
    const float* __restrict__ bias,          // (4,512)
    float* __restrict__ out)                 // (4096,512)
{
    __shared__ unsigned short As[2 * BM * BK];        // 2 x 8 KB
    __shared__ unsigned short Bs[2 * NK * BN * BK];   // 2 x 32 KB

    const int tid  = threadIdx.x;
    const int lane = tid & 63;
    const int wid  = tid >> 6;
    const int wr   = (wid >> 1) * 32;
    const int wc   = (wid & 1) * 32;
    const int bid  = blockIdx.x;
    const int R0   = (bid >> 3) * BM;      // 64 row-tiles per column
    const int C0   = (bid & 7) * BN;       // column == XCD (round-robin dispatch)

    f32x4 acc[NK][2][2] = {};
    const int cl = lane & 15;
    const int kb = (lane >> 4) * 8;

    auto stage = [&](int b, int k0) {
        #pragma unroll
        for (int j = 0; j < 2; ++j) {
            int ch  = j * 256 + tid;
            int row = ch >> 3;
            int c   = ch & 7;
            gload_lds16(fb + (size_t)(R0 + row) * IN_DIM + k0 + ((c ^ (row & 7)) << 3),
                        &As[b * BM * BK + ch * 8]);
        }
        #pragma unroll
        for (int j = 0; j < 8; ++j) {
            int ch  = j * 256 + tid;
            int kn  = ch >> 9;
            int rem = ch & 511;
            int row = rem >> 3;
            int c   = rem & 7;
            gload_lds16(wb + (size_t)kn * OUT_DIM * IN_DIM + (size_t)(C0 + row) * IN_DIM
                           + k0 + ((c ^ (row & 7)) << 3),
                        &Bs[b * NK * BN * BK + ch * 8]);
        }
    };

    auto compute = [&](int b) {
        const char* Ab = reinterpret_cast<const char*>(As) + b * BM * BK * 2;
        const char* Bb = reinterpret_cast<const char*>(Bs) + b * NK * BN * BK * 2;
        #pragma unroll
        for (int kk = 0; kk < BK; kk += 32) {
            bf16x8 af[2];
            #pragma unroll
            for (int m = 0; m < 2; ++m) {
                int row  = wr + m * 16 + cl;
                int boff = (row * 128 + (kk + kb) * 2) ^ ((row & 7) << 4);
                af[m] = *reinterpret_cast<const bf16x8*>(Ab + boff);
            }
            #pragma unroll
            for (int kn = 0; kn < NK; ++kn) {
                bf16x8 bfr[2];
                #pragma unroll
                for (int n = 0; n < 2; ++n) {
                    int row  = wc + n * 16 + cl;
                    int boff = (row * 128 + (kk + kb) * 2) ^ ((row & 7) << 4);
                    bfr[n] = *reinterpret_cast<const bf16x8*>(Bb + kn * 8192 + boff);
                }
                __builtin_amdgcn_s_setprio(1);
                #pragma unroll
                for (int m = 0; m < 2; ++m)
                    #pragma unroll
                    for (int n = 0; n < 2; ++n)
                        acc[kn][m][n] = __builtin_amdgcn_mfma_f32_16x16x32_bf16(
                            af[m], bfr[n], acc[kn][m][n], 0, 0, 0);
                __builtin_amdgcn_s_setprio(0);
            }
        }
    };

    stage(0, 0);
    stage(1, BK);
    #pragma unroll
    for (int kt = 0; kt < KT; ++kt) {
        const int cur = kt & 1;
        if (kt < KT - 1) asm volatile("s_waitcnt vmcnt(10)" ::: "memory");
        else             asm volatile("s_waitcnt vmcnt(0)"  ::: "memory");
        __builtin_amdgcn_s_barrier();
        compute(cur);
        __builtin_amdgcn_s_barrier();
        if (kt < KT - 2) stage(cur, (kt + 2) * BK);
    }

    const int rl = (lane >> 4) * 4;
    float bcol[2][NK];
    #pragma unroll
    for (int n = 0; n < 2; ++n)
        #pragma unroll
        for (int k = 0; k < NK; ++k)
            bcol[n][k] = bias[k * OUT_DIM + C0 + wc + n * 16 + cl];

    #pragma unroll
    for (int m = 0; m < 2; ++m) {
        #pragma unroll
        for (int r = 0; r < 4; ++r) {
            const int row = R0 + wr + m * 16 + rl + r;
            const float4 p = *reinterpret_cast<const float4*>(&x[(size_t)row * SX + IN_DIM]);
            const float pk[4] = {p.x, p.y, p.z, p.w};
            #pragma unroll
            for (int n = 0; n < 2; ++n) {
                float v = 0.f;
                #pragma unroll
                for (int k = 0; k < NK; ++k)
                    v += pk[k] * (acc[k][m][n][r] + bcol[n][k]);
                v = (v > 0.f) ? v : expm1f(v);
                out[(size_t)row * OUT_DIM + C0 + wc + n * 16 + cl] = v;
            }
        }
    }
}

// ---------------- fallback (round-1 kernel) if ws too small ----------------
#define LDT 72
__global__ __launch_bounds__(256) void mpl_kernel_fb(
    const float* __restrict__ x, const float* __restrict__ w,
    const float* __restrict__ bias, float* __restrict__ out)
{
    __shared__ unsigned short Asf[BM][LDT];
    __shared__ unsigned short Bsf[NK][64][LDT];
    const int tid = threadIdx.x, lane = tid & 63, wid = tid >> 6;
    const int wr = (wid >> 1) * 32, wc = (wid & 1) * 32;
    const int R0 = blockIdx.x * BM, C0 = blockIdx.y * 64;
    f32x4 acc[NK][2][2] = {};
    const int cl = lane & 15, kb = (lane >> 4) * 8;
    for (int kt = 0; kt < KT; ++kt) {
        const int k0 = kt * BK;
        __syncthreads();
        #pragma unroll
        for (int j = 0; j < 4; ++j) {
            int f = tid + 256 * j, row = f >> 4, c4 = (f & 15) * 4;
            const float4 v = *reinterpret_cast<const float4*>(&x[(size_t)(R0 + row) * SX + k0 + c4]);
            unsigned short h[4] = {f2bf(v.x), f2bf(v.y), f2bf(v.z), f2bf(v.w)};
            *reinterpret_cast<uint2*>(&Asf[row][c4]) = *reinterpret_cast<const uint2*>(h);
        }
        #pragma unroll
        for (int kn = 0; kn < NK; ++kn)
            #pragma unroll
            for (int j = 0; j < 4; ++j) {
                int f = tid + 256 * j, row = f >> 4, c4 = (f & 15) * 4;
                const float4 v = *reinterpret_cast<const float4*>(
                    &w[(size_t)kn * OUT_DIM * IN_DIM + (size_t)(C0 + row) * IN_DIM + k0 + c4]);
                unsigned short h[4] = {f2bf(v.x), f2bf(v.y), f2bf(v.z), f2bf(v.w)};
                *reinterpret_cast<uint2*>(&Bsf[kn][row][c4]) = *reinterpret_cast<const uint2*>(h);
            }
        __syncthreads();
        #pragma unroll
        for (int kk = 0; kk < BK; kk += 32) {
            bf16x8 af[2];
            #pragma unroll
            for (int m = 0; m < 2; ++m)
                af[m] = *reinterpret_cast<const bf16x8*>(&Asf[wr + m * 16 + cl][kk + kb]);
            #pragma unroll
            for (int kn = 0; kn < NK; ++kn) {
                bf16x8 bfr[2];
                #pragma unroll
                for (int n = 0; n < 2; ++n)
                    bfr[n] = *reinterpret_cast<const bf16x8*>(&Bsf[kn][wc + n * 16 + cl][kk + kb]);
                #pragma unroll
                for (int m = 0; m < 2; ++m)
                    #pragma unroll
                    for (int n = 0; n < 2; ++n)
                        acc[kn][m][n] = __builtin_amdgcn_mfma_f32_16x16x32_bf16(
                            af[m], bfr[n], acc[kn][m][n], 0, 0, 0);
            }
        }
    }
    const int rl = (lane >> 4) * 4;
    float bcol[2][NK];
    #pragma unroll
    for (int n = 0; n < 2; ++n)
        #pragma unroll
        for (int k = 0; k < NK; ++k)
            bcol[n][k] = bias[k * OUT_DIM + C0 + wc + n * 16 + cl];
    #pragma unroll
    for (int m = 0; m < 2; ++m)
        #pragma unroll
        for (int r = 0; r < 4; ++r) {
            const int row = R0 + wr + m * 16 + rl + r;
            const float4 p = *reinterpret_cast<const float4*>(&x[(size_t)row * SX + IN_DIM]);
            const float pk[4] = {p.x, p.y, p.z, p.w};
            #pragma unroll
            for (int n = 0; n < 2; ++n) {
                float v = 0.f;
                #pragma unroll
                for (int k = 0; k < NK; ++k)
                    v += pk[k] * (acc[k][m][n][r] + bcol[n][k]);
                v = (v > 0.f) ? v : expm1f(v);
                out[(size_t)row * OUT_DIM + C0 + wc + n * 16 + cl] = v;
            }
        }
}

extern "C" void kernel_launch(void* const* d_in, const int* in_sizes, int n_in,
                              void* d_out, int out_size, void* d_ws, size_t ws_size,
                              hipStream_t stream) {
    const float* x    = (const float*)d_in[0];
    const float* w    = (const float*)d_in[1];
    const float* bias = (const float*)d_in[2];
    float* out        = (float*)d_out;

    const size_t wb_bytes = (size_t)NK * OUT_DIM * IN_DIM * 2;   // 2 MB
    const size_t fb_bytes = (size_t)BATCH * IN_DIM * 2;          // 4 MB

    if (ws_size < wb_bytes + fb_bytes) {
        dim3 grid(BATCH / BM, OUT_DIM / 64);
        mpl_kernel_fb<<<grid, dim3(256), 0, stream>>>(x, w, bias, out);
        return;
    }

    unsigned short* wb = (unsigned short*)d_ws;
    unsigned short* fb = (unsigned short*)((char*)d_ws + wb_bytes);

    convert_kernel<<<dim3(3072), dim3(256), 0, stream>>>(x, w, wb, fb);

    mpl_gemm<<<dim3((BATCH / BM) * (OUT_DIM / BN)), dim3(256), 0, stream>>>(fb, wb, x, bias, out);

    // ---- DIAGNOSTIC replica: warm-cache GEMM into scratch. total = c + g_cold + g_warm.
    // Outcome decodes the bottleneck: ~29us -> overhead-bound; ~38us -> traffic-bound;
    // ~47us -> execution-pipe-bound.
    if (ws_size >= (size_t)48 * 1024 * 1024) {
        float* out2 = (float*)((char*)d_ws + (size_t)32 * 1024 * 1024);
        mpl_gemm<<<dim3((BATCH / BM) * (OUT_DIM / BN)), dim3(256), 0, stream>>>(fb, wb, x, bias, out2);
    }
}

// Round 9
// 36.626 us; speedup vs baseline: 1.2454x; 1.2454x over previous
//
#include <hip/hip_runtime.h>

#define BATCH 4096
#define IN_DIM 512
#define OUT_DIM 512
#define NK 4
#define SX (IN_DIM + NK)   // 516 floats per x row
#define BM 64
#define BN 64
#define BK 32
#define KT2 (IN_DIM / BK)  // 16 K-tiles

typedef short bf16x8 __attribute__((ext_vector_type(8)));
typedef float f32x4 __attribute__((ext_vector_type(4)));

__device__ __forceinline__ unsigned short f2bf(float f) {
    unsigned int u = __float_as_uint(f);
    u = u + 0x7FFFu + ((u >> 16) & 1u);   // round-to-nearest-even
    return (unsigned short)(u >> 16);
}

__device__ __forceinline__ void gload_lds16(const void* g, void* l) {
    __builtin_amdgcn_global_load_lds(
        (const __attribute__((address_space(1))) void*)g,
        (__attribute__((address_space(3))) void*)l, 16, 0, 0);
}

// ---------------- kernel 1: fp32 -> bf16 pre-pass ----------------
__global__ __launch_bounds__(256) void convert_kernel(
    const float* __restrict__ x, const float* __restrict__ w,
    unsigned short* __restrict__ wb, unsigned short* __restrict__ fb)
{
    const int WCH = NK * OUT_DIM * IN_DIM / 4;   // 262144 float4 chunks of W
    int g = blockIdx.x * 256 + threadIdx.x;
    if (g < WCH) {
        const float4 v = reinterpret_cast<const float4*>(w)[g];
        unsigned short h[4] = {f2bf(v.x), f2bf(v.y), f2bf(v.z), f2bf(v.w)};
        *reinterpret_cast<uint2*>(&wb[g * 4]) = *reinterpret_cast<const uint2*>(h);
    } else {
        int idx = g - WCH;                        // feat chunks: 4096*128
        int row = idx >> 7;
        int c   = (idx & 127) * 4;
        const float4 v = *reinterpret_cast<const float4*>(&x[(size_t)row * SX + c]);
        unsigned short h[4] = {f2bf(v.x), f2bf(v.y), f2bf(v.z), f2bf(v.w)};
        *reinterpret_cast<uint2*>(&fb[row * IN_DIM + c]) = *reinterpret_cast<const uint2*>(h);
    }
}

// ------- kernel 2: BK=32, 4 blocks/CU (16 waves/CU), K-slab-major LDS -------
// LDS layout: chunk d = c*64 + row (A) / kn*256 + c*64 + col (B), 16B chunks.
// Reads are conflict-free by construction (contiguous 256B per 16-lane group).
// Staging: dest = linear by tid; source scattered (16B per row-line) -> L2.
__global__ __launch_bounds__(256, 4) void mpl_gemm(
    const unsigned short* __restrict__ fb,   // (4096,512) bf16
    const unsigned short* __restrict__ wb,   // (4,512,512) bf16
    const float* __restrict__ x,             // (4096,516) fp32 (for p)
    const float* __restrict__ bias,          // (4,512)
    float* __restrict__ out)                 // (4096,512)
{
    __shared__ unsigned short As[2 * BM * BK];        // 2 x 4 KB
    __shared__ unsigned short Bs[2 * NK * BN * BK];   // 2 x 16 KB

    const int tid  = threadIdx.x;
    const int lane = tid & 63;
    const int wid  = tid >> 6;
    const int wr   = (wid >> 1) * 32;
    const int wc   = (wid & 1) * 32;
    const int R0   = blockIdx.x * BM;
    const int C0   = blockIdx.y * BN;

    f32x4 acc[NK][2][2] = {};
    const int cl    = lane & 15;
    const int cslab = lane >> 4;           // K-slab 0..3 (8 elems each)

    // ---- stage: 5 gload_lds per thread (1 A + 4 B) for K-tile k0 ----
    auto stage = [&](int b, int k0) {
        {   // A: chunk d = tid; row = tid&63, c = tid>>6 (wave-uniform)
            int row = tid & 63;
            int c   = tid >> 6;
            gload_lds16(fb + (size_t)(R0 + row) * IN_DIM + k0 + c * 8,
                        &As[b * BM * BK + tid * 8]);
        }
        #pragma unroll
        for (int kn = 0; kn < NK; ++kn) {
            // B: col = tid&63, c = tid>>6; dest chunk d = kn*256 + c*64 + col
            int col = tid & 63;
            int c   = tid >> 6;
            gload_lds16(wb + (size_t)kn * OUT_DIM * IN_DIM + (size_t)(C0 + col) * IN_DIM
                           + k0 + c * 8,
                        &Bs[b * NK * BN * BK + (kn * 256 + tid) * 8]);
        }
    };

    auto compute = [&](int b) {
        const unsigned short* Ab = As + b * BM * BK;
        const unsigned short* Bb = Bs + b * NK * BN * BK;
        bf16x8 af[2];
        #pragma unroll
        for (int m = 0; m < 2; ++m)
            af[m] = *reinterpret_cast<const bf16x8*>(
                &Ab[cslab * 512 + (wr + m * 16 + cl) * 8]);
        #pragma unroll
        for (int kn = 0; kn < NK; ++kn) {
            bf16x8 bfr[2];
            #pragma unroll
            for (int n = 0; n < 2; ++n)
                bfr[n] = *reinterpret_cast<const bf16x8*>(
                    &Bb[kn * 2048 + cslab * 512 + (wc + n * 16 + cl) * 8]);
            __builtin_amdgcn_s_setprio(1);
            #pragma unroll
            for (int m = 0; m < 2; ++m)
                #pragma unroll
                for (int n = 0; n < 2; ++n)
                    acc[kn][m][n] = __builtin_amdgcn_mfma_f32_16x16x32_bf16(
                        af[m], bfr[n], acc[kn][m][n], 0, 0, 0);
            __builtin_amdgcn_s_setprio(0);
        }
    };

    // ---- prologue: 2-deep prefetch (10 loads in flight per thread) ----
    stage(0, 0);
    stage(1, BK);
    for (int kt = 0; kt < KT2; ++kt) {
        const int cur = kt & 1;
        if (kt < KT2 - 1) asm volatile("s_waitcnt vmcnt(5)" ::: "memory");
        else              asm volatile("s_waitcnt vmcnt(0)" ::: "memory");
        __builtin_amdgcn_s_barrier();     // tile-kt loads visible to all waves
        compute(cur);
        __builtin_amdgcn_s_barrier();     // WAR: all waves done reading buf cur
        if (kt < KT2 - 2) stage(cur, (kt + 2) * BK);
    }

    // ---- epilogue: res = sum_k p[b,k]*(acc_k + bias_k[o]); elu ----
    const int rl = (lane >> 4) * 4;
    float bcol[2][NK];
    #pragma unroll
    for (int n = 0; n < 2; ++n)
        #pragma unroll
        for (int k = 0; k < NK; ++k)
            bcol[n][k] = bias[k * OUT_DIM + C0 + wc + n * 16 + cl];

    #pragma unroll
    for (int m = 0; m < 2; ++m) {
        #pragma unroll
        for (int r = 0; r < 4; ++r) {
            const int row = R0 + wr + m * 16 + rl + r;
            const float4 p = *reinterpret_cast<const float4*>(&x[(size_t)row * SX + IN_DIM]);
            const float pk[4] = {p.x, p.y, p.z, p.w};
            #pragma unroll
            for (int n = 0; n < 2; ++n) {
                float v = 0.f;
                #pragma unroll
                for (int k = 0; k < NK; ++k)
                    v += pk[k] * (acc[k][m][n][r] + bcol[n][k]);
                v = (v > 0.f) ? v : expm1f(v);
                out[(size_t)row * OUT_DIM + C0 + wc + n * 16 + cl] = v;
            }
        }
    }
}

// ---------------- fallback (round-1 kernel) if ws too small ----------------
#define LDT 72
__global__ __launch_bounds__(256) void mpl_kernel_fb(
    const float* __restrict__ x, const float* __restrict__ w,
    const float* __restrict__ bias, float* __restrict__ out)
{
    __shared__ unsigned short Asf[BM][LDT];
    __shared__ unsigned short Bsf[NK][64][LDT];
    const int tid = threadIdx.x, lane = tid & 63, wid = tid >> 6;
    const int wr = (wid >> 1) * 32, wc = (wid & 1) * 32;
    const int R0 = blockIdx.x * BM, C0 = blockIdx.y * 64;
    f32x4 acc[NK][2][2] = {};
    const int cl = lane & 15, kb = (lane >> 4) * 8;
    for (int kt = 0; kt < IN_DIM / 64; ++kt) {
        const int k0 = kt * 64;
        __syncthreads();
        #pragma unroll
        for (int j = 0; j < 4; ++j) {
            int f = tid + 256 * j, row = f >> 4, c4 = (f & 15) * 4;
            const float4 v = *reinterpret_cast<const float4*>(&x[(size_t)(R0 + row) * SX + k0 + c4]);
            unsigned short h[4] = {f2bf(v.x), f2bf(v.y), f2bf(v.z), f2bf(v.w)};
            *reinterpret_cast<uint2*>(&Asf[row][c4]) = *reinterpret_cast<const uint2*>(h);
        }
        #pragma unroll
        for (int kn = 0; kn < NK; ++kn)
            #pragma unroll
            for (int j = 0; j < 4; ++j) {
                int f = tid + 256 * j, row = f >> 4, c4 = (f & 15) * 4;
                const float4 v = *reinterpret_cast<const float4*>(
                    &w[(size_t)kn * OUT_DIM * IN_DIM + (size_t)(C0 + row) * IN_DIM + k0 + c4]);
                unsigned short h[4] = {f2bf(v.x), f2bf(v.y), f2bf(v.z), f2bf(v.w)};
                *reinterpret_cast<uint2*>(&Bsf[kn][row][c4]) = *reinterpret_cast<const uint2*>(h);
            }
        __syncthreads();
        #pragma unroll
        for (int kk = 0; kk < 64; kk += 32) {
            bf16x8 af[2];
            #pragma unroll
            for (int m = 0; m < 2; ++m)
                af[m] = *reinterpret_cast<const bf16x8*>(&Asf[wr + m * 16 + cl][kk + kb]);
            #pragma unroll
            for (int kn = 0; kn < NK; ++kn) {
                bf16x8 bfr[2];
                #pragma unroll
                for (int n = 0; n < 2; ++n)
                    bfr[n] = *reinterpret_cast<const bf16x8*>(&Bsf[kn][wc + n * 16 + cl][kk + kb]);
                #pragma unroll
                for (int m = 0; m < 2; ++m)
                    #pragma unroll
                    for (int n = 0; n < 2; ++n)
                        acc[kn][m][n] = __builtin_amdgcn_mfma_f32_16x16x32_bf16(
                            af[m], bfr[n], acc[kn][m][n], 0, 0, 0);
            }
        }
    }
    const int rl = (lane >> 4) * 4;
    float bcol[2][NK];
    #pragma unroll
    for (int n = 0; n < 2; ++n)
        #pragma unroll
        for (int k = 0; k < NK; ++k)
            bcol[n][k] = bias[k * OUT_DIM + C0 + wc + n * 16 + cl];
    #pragma unroll
    for (int m = 0; m < 2; ++m)
        #pragma unroll
        for (int r = 0; r < 4; ++r) {
            const int row = R0 + wr + m * 16 + rl + r;
            const float4 p = *reinterpret_cast<const float4*>(&x[(size_t)row * SX + IN_DIM]);
            const float pk[4] = {p.x, p.y, p.z, p.w};
            #pragma unroll
            for (int n = 0; n < 2; ++n) {
                float v = 0.f;
                #pragma unroll
                for (int k = 0; k < NK; ++k)
                    v += pk[k] * (acc[k][m][n][r] + bcol[n][k]);
                v = (v > 0.f) ? v : expm1f(v);
                out[(size_t)row * OUT_DIM + C0 + wc + n * 16 + cl] = v;
            }
        }
}

extern "C" void kernel_launch(void* const* d_in, const int* in_sizes, int n_in,
                              void* d_out, int out_size, void* d_ws, size_t ws_size,
                              hipStream_t stream) {
    const float* x    = (const float*)d_in[0];
    const float* w    = (const float*)d_in[1];
    const float* bias = (const float*)d_in[2];
    float* out        = (float*)d_out;

    const size_t wb_bytes = (size_t)NK * OUT_DIM * IN_DIM * 2;   // 2 MB
    const size_t fb_bytes = (size_t)BATCH * IN_DIM * 2;          // 4 MB

    if (ws_size < wb_bytes + fb_bytes) {
        dim3 grid(BATCH / BM, OUT_DIM / 64);
        mpl_kernel_fb<<<grid, dim3(256), 0, stream>>>(x, w, bias, out);
        return;
    }

    unsigned short* wb = (unsigned short*)d_ws;
    unsigned short* fb = (unsigned short*)((char*)d_ws + wb_bytes);

    const int total_chunks = NK * OUT_DIM * IN_DIM / 4 + BATCH * IN_DIM / 4;  // 786432
    convert_kernel<<<dim3(total_chunks / 256), dim3(256), 0, stream>>>(x, w, wb, fb);

    dim3 grid(BATCH / BM, OUT_DIM / BN);
    mpl_gemm<<<grid, dim3(256), 0, stream>>>(fb, wb, x, bias, out);
}

// Round 10
// 29.305 us; speedup vs baseline: 1.5565x; 1.2498x over previous
//
#include <hip/hip_runtime.h>

#define BATCH 4096
#define IN_DIM 512
#define OUT_DIM 512
#define NK 4
#define SX (IN_DIM + NK)   // 516 floats per x row
#define BM 64
#define BN 64
#define BK 64
#define KT (IN_DIM / BK)   // 8 K-tiles

typedef short bf16x8 __attribute__((ext_vector_type(8)));
typedef float f32x4 __attribute__((ext_vector_type(4)));

__device__ __forceinline__ unsigned short f2bf(float f) {
    unsigned int u = __float_as_uint(f);
    u = u + 0x7FFFu + ((u >> 16) & 1u);   // round-to-nearest-even
    return (unsigned short)(u >> 16);
}

__device__ __forceinline__ void gload_lds16(const void* g, void* l) {
    __builtin_amdgcn_global_load_lds(
        (const __attribute__((address_space(1))) void*)g,
        (__attribute__((address_space(3))) void*)l, 16, 0, 0);
}

// ---------------- kernel 1: fp32 -> bf16 pre-pass (W ONLY, 2 MB) ----------------
__global__ __launch_bounds__(256) void convert_kernel(
    const float* __restrict__ w, unsigned short* __restrict__ wb)
{
    int g = blockIdx.x * 256 + threadIdx.x;          // 262144 float4 chunks
    const float4 v = reinterpret_cast<const float4*>(w)[g];
    unsigned short h[4] = {f2bf(v.x), f2bf(v.y), f2bf(v.z), f2bf(v.w)};
    *reinterpret_cast<uint2*>(&wb[g * 4]) = *reinterpret_cast<const uint2*>(h);
}

// ------- kernel 2: GEMM; B via 2-deep gload_lds, A fused fp32->bf16 reg-stage -------
__global__ __launch_bounds__(256) void mpl_gemm(
    const unsigned short* __restrict__ wb,   // (4,512,512) bf16
    const float* __restrict__ x,             // (4096,516) fp32 (feat + p)
    const float* __restrict__ bias,          // (4,512)
    float* __restrict__ out)                 // (4096,512)
{
    __shared__ unsigned short As[2 * BM * BK];        // 2 x 8 KB (swizzled content)
    __shared__ unsigned short Bs[2 * NK * BN * BK];   // 2 x 32 KB (swizzled content)

    const int tid  = threadIdx.x;
    const int lane = tid & 63;
    const int wid  = tid >> 6;
    const int wr   = (wid >> 1) * 32;
    const int wc   = (wid & 1) * 32;
    const int R0   = blockIdx.x * BM;
    const int C0   = blockIdx.y * BN;

    f32x4 acc[NK][2][2] = {};
    const int cl = lane & 15;
    const int kb = (lane >> 4) * 8;

    const int arow = tid >> 2;            // A stage: this thread's row (0..63)
    const int akq  = tid & 3;             // 16-elem quad within the 64-K row

    float4 areg[2][4];                    // 1-deep A double-buffer (static idx only)

    auto BSTAGE = [&](int b, int k0) {    // 8 gload_lds per thread
        #pragma unroll
        for (int j = 0; j < 8; ++j) {
            int ch  = j * 256 + tid;
            int kn  = ch >> 9;
            int rem = ch & 511;
            int row = rem >> 3;
            int c   = rem & 7;
            gload_lds16(wb + (size_t)kn * OUT_DIM * IN_DIM + (size_t)(C0 + row) * IN_DIM
                           + k0 + ((c ^ (row & 7)) << 3),
                        &Bs[b * NK * BN * BK + ch * 8]);
        }
    };
    auto ALOAD = [&](int pa, int ktile) { // 4 global float4 loads per thread
        #pragma unroll
        for (int j = 0; j < 4; ++j)
            areg[pa][j] = *reinterpret_cast<const float4*>(
                &x[(size_t)(R0 + arow) * SX + ktile * BK + akq * 16 + j * 4]);
    };
    auto AWRITE = [&](int pa, int b) {    // cvt 16 fp32 -> bf16, 2 ds_write_b128
        unsigned short h[16];
        #pragma unroll
        for (int j = 0; j < 4; ++j) {
            h[j * 4 + 0] = f2bf(areg[pa][j].x);
            h[j * 4 + 1] = f2bf(areg[pa][j].y);
            h[j * 4 + 2] = f2bf(areg[pa][j].z);
            h[j * 4 + 3] = f2bf(areg[pa][j].w);
        }
        char* base = reinterpret_cast<char*>(As) + b * 8192;
        int o0 = (arow * 128 + akq * 32)      ^ ((arow & 7) << 4);
        int o1 = (arow * 128 + akq * 32 + 16) ^ ((arow & 7) << 4);
        *reinterpret_cast<bf16x8*>(base + o0) = *reinterpret_cast<const bf16x8*>(&h[0]);
        *reinterpret_cast<bf16x8*>(base + o1) = *reinterpret_cast<const bf16x8*>(&h[8]);
    };

    auto compute = [&](int b) {
        const char* Ab = reinterpret_cast<const char*>(As) + b * BM * BK * 2;
        const char* Bb = reinterpret_cast<const char*>(Bs) + b * NK * BN * BK * 2;
        #pragma unroll
        for (int kk = 0; kk < BK; kk += 32) {
            bf16x8 af[2];
            #pragma unroll
            for (int m = 0; m < 2; ++m) {
                int row  = wr + m * 16 + cl;
                int boff = (row * 128 + (kk + kb) * 2) ^ ((row & 7) << 4);
                af[m] = *reinterpret_cast<const bf16x8*>(Ab + boff);
            }
            #pragma unroll
            for (int kn = 0; kn < NK; ++kn) {
                bf16x8 bfr[2];
                #pragma unroll
                for (int n = 0; n < 2; ++n) {
                    int row  = wc + n * 16 + cl;
                    int boff = (row * 128 + (kk + kb) * 2) ^ ((row & 7) << 4);
                    bfr[n] = *reinterpret_cast<const bf16x8*>(Bb + kn * 8192 + boff);
                }
                __builtin_amdgcn_s_setprio(1);
                #pragma unroll
                for (int m = 0; m < 2; ++m)
                    #pragma unroll
                    for (int n = 0; n < 2; ++n)
                        acc[kn][m][n] = __builtin_amdgcn_mfma_f32_16x16x32_bf16(
                            af[m], bfr[n], acc[kn][m][n], 0, 0, 0);
                __builtin_amdgcn_s_setprio(0);
            }
        }
    };

    // ---- prologue ----
    ALOAD(0, 0);                                   // [A0]=4
    BSTAGE(0, 0);                                  // [B0]=8
    BSTAGE(1, BK);                                 // [B1]=8  (inflight 20)
    asm volatile("s_waitcnt vmcnt(16)" ::: "memory");   // A0 regs ready
    AWRITE(0, 0);                                  // A(0) -> buf0
    ALOAD(1, 1);                                   // [A1]=4  (inflight B0,B1,A1)

    // ---- K-loop; ledger (per thread): BSTAGE=8, ALOAD=4 ----
    for (int kt = 0; kt < KT; ++kt) {
        const int cur = kt & 1;
        // X1: ensure B(kt) in LDS. inflight: B(kt+1)=8 + A(kt+1)=4 (when kt<7).
        if (kt < KT - 1) asm volatile("s_waitcnt vmcnt(12)" ::: "memory");
        else             asm volatile("s_waitcnt vmcnt(0)"  ::: "memory");
        asm volatile("s_waitcnt lgkmcnt(0)" ::: "memory");  // publish A(kt) writes
        __builtin_amdgcn_s_barrier();
        compute(cur);
        __builtin_amdgcn_s_barrier();              // WAR on buf cur
        if (kt + 2 < KT) BSTAGE(cur, (kt + 2) * BK);        // [B(kt+2)]=8
        if (kt + 1 < KT) {
            // X2: A(kt+1) regs ready. inflight: B(kt+1),A(kt+1),[B(kt+2)] -> leave B(kt+2)
            if (kt + 2 < KT) asm volatile("s_waitcnt vmcnt(8)" ::: "memory");
            else             asm volatile("s_waitcnt vmcnt(0)" ::: "memory");
            if ((kt + 1) & 1) AWRITE(1, 1); else AWRITE(0, 0);   // A(kt+1) -> buf (kt+1)&1
            if (kt + 2 < KT) { if (kt & 1) ALOAD(1, kt + 2); else ALOAD(0, kt + 2); }
        }
    }

    // ---- epilogue: res = sum_k p[b,k]*(acc_k + bias_k[o]); elu ----
    const int rl = (lane >> 4) * 4;
    float bcol[2][NK];
    #pragma unroll
    for (int n = 0; n < 2; ++n)
        #pragma unroll
        for (int k = 0; k < NK; ++k)
            bcol[n][k] = bias[k * OUT_DIM + C0 + wc + n * 16 + cl];

    #pragma unroll
    for (int m = 0; m < 2; ++m) {
        #pragma unroll
        for (int r = 0; r < 4; ++r) {
            const int row = R0 + wr + m * 16 + rl + r;
            const float4 p = *reinterpret_cast<const float4*>(&x[(size_t)row * SX + IN_DIM]);
            const float pk[4] = {p.x, p.y, p.z, p.w};
            #pragma unroll
            for (int n = 0; n < 2; ++n) {
                float v = 0.f;
                #pragma unroll
                for (int k = 0; k < NK; ++k)
                    v += pk[k] * (acc[k][m][n][r] + bcol[n][k]);
                v = (v > 0.f) ? v : expm1f(v);
                out[(size_t)row * OUT_DIM + C0 + wc + n * 16 + cl] = v;
            }
        }
    }
}

// ---------------- fallback (round-1 kernel, fp32 inputs) if ws too small ----------------
#define LDT 72
__global__ __launch_bounds__(256) void mpl_kernel_fb(
    const float* __restrict__ x, const float* __restrict__ w,
    const float* __restrict__ bias, float* __restrict__ out)
{
    __shared__ unsigned short Asf[BM][LDT];
    __shared__ unsigned short Bsf[NK][64][LDT];
    const int tid = threadIdx.x, lane = tid & 63, wid = tid >> 6;
    const int wr = (wid >> 1) * 32, wc = (wid & 1) * 32;
    const int R0 = blockIdx.x * BM, C0 = blockIdx.y * 64;
    f32x4 acc[NK][2][2] = {};
    const int cl = lane & 15, kb = (lane >> 4) * 8;
    for (int kt = 0; kt < KT; ++kt) {
        const int k0 = kt * BK;
        __syncthreads();
        #pragma unroll
        for (int j = 0; j < 4; ++j) {
            int f = tid + 256 * j, row = f >> 4, c4 = (f & 15) * 4;
            const float4 v = *reinterpret_cast<const float4*>(&x[(size_t)(R0 + row) * SX + k0 + c4]);
            unsigned short h[4] = {f2bf(v.x), f2bf(v.y), f2bf(v.z), f2bf(v.w)};
            *reinterpret_cast<uint2*>(&Asf[row][c4]) = *reinterpret_cast<const uint2*>(h);
        }
        #pragma unroll
        for (int kn = 0; kn < NK; ++kn)
            #pragma unroll
            for (int j = 0; j < 4; ++j) {
                int f = tid + 256 * j, row = f >> 4, c4 = (f & 15) * 4;
                const float4 v = *reinterpret_cast<const float4*>(
                    &w[(size_t)kn * OUT_DIM * IN_DIM + (size_t)(C0 + row) * IN_DIM + k0 + c4]);
                unsigned short h[4] = {f2bf(v.x), f2bf(v.y), f2bf(v.z), f2bf(v.w)};
                *reinterpret_cast<uint2*>(&Bsf[kn][row][c4]) = *reinterpret_cast<const uint2*>(h);
            }
        __syncthreads();
        #pragma unroll
        for (int kk = 0; kk < BK; kk += 32) {
            bf16x8 af[2];
            #pragma unroll
            for (int m = 0; m < 2; ++m)
                af[m] = *reinterpret_cast<const bf16x8*>(&Asf[wr + m * 16 + cl][kk + kb]);
            #pragma unroll
            for (int kn = 0; kn < NK; ++kn) {
                bf16x8 bfr[2];
                #pragma unroll
                for (int n = 0; n < 2; ++n)
                    bfr[n] = *reinterpret_cast<const bf16x8*>(&Bsf[kn][wc + n * 16 + cl][kk + kb]);
                #pragma unroll
                for (int m = 0; m < 2; ++m)
                    #pragma unroll
                    for (int n = 0; n < 2; ++n)
                        acc[kn][m][n] = __builtin_amdgcn_mfma_f32_16x16x32_bf16(
                            af[m], bfr[n], acc[kn][m][n], 0, 0, 0);
            }
        }
    }
    const int rl = (lane >> 4) * 4;
    float bcol[2][NK];
    #pragma unroll
    for (int n = 0; n < 2; ++n)
        #pragma unroll
        for (int k = 0; k < NK; ++k)
            bcol[n][k] = bias[k * OUT_DIM + C0 + wc + n * 16 + cl];
    #pragma unroll
    for (int m = 0; m < 2; ++m)
        #pragma unroll
        for (int r = 0; r < 4; ++r) {
            const int row = R0 + wr + m * 16 + rl + r;
            const float4 p = *reinterpret_cast<const float4*>(&x[(size_t)row * SX + IN_DIM]);
            const float pk[4] = {p.x, p.y, p.z, p.w};
            #pragma unroll
            for (int n = 0; n < 2; ++n) {
                float v = 0.f;
                #pragma unroll
                for (int k = 0; k < NK; ++k)
                    v += pk[k] * (acc[k][m][n][r] + bcol[n][k]);
                v = (v > 0.f) ? v : expm1f(v);
                out[(size_t)row * OUT_DIM + C0 + wc + n * 16 + cl] = v;
            }
        }
}

extern "C" void kernel_launch(void* const* d_in, const int* in_sizes, int n_in,
                              void* d_out, int out_size, void* d_ws, size_t ws_size,
                              hipStream_t stream) {
    const float* x    = (const float*)d_in[0];
    const float* w    = (const float*)d_in[1];
    const float* bias = (const float*)d_in[2];
    float* out        = (float*)d_out;

    const size_t wb_bytes = (size_t)NK * OUT_DIM * IN_DIM * 2;   // 2 MB

    if (ws_size < wb_bytes) {
        dim3 grid(BATCH / BM, OUT_DIM / 64);
        mpl_kernel_fb<<<grid, dim3(256), 0, stream>>>(x, w, bias, out);
        return;
    }

    unsigned short* wb = (unsigned short*)d_ws;

    // W-only convert: 262144 float4 chunks / 256 = 1024 blocks
    convert_kernel<<<dim3(NK * OUT_DIM * IN_DIM / 4 / 256), dim3(256), 0, stream>>>(w, wb);

    dim3 grid(BATCH / BM, OUT_DIM / BN);
    mpl_gemm<<<grid, dim3(256), 0, stream>>>(wb, x, bias, out);
}